// Round 1
// baseline (305.032 us; speedup 1.0000x reference)
//
#include <hip/hip_runtime.h>
#include <hip/hip_bf16.h>

#define B_ 8
#define N_ 2048
#define D_ 128
#define NROW (B_*N_)   // 16384

typedef __bf16 bf16;
typedef __bf16 bf16x8 __attribute__((ext_vector_type(8)));
typedef float f32x4 __attribute__((ext_vector_type(4)));

__device__ __forceinline__ float sigmoidf_(float x) {
    return 1.0f / (1.0f + __expf(-x));
}

// ---------------- K0: transpose W_qk, W_l, W_r -> bf16 [out][in] ----------------
__global__ __launch_bounds__(256) void k_wtrans(const float* __restrict__ Wqk,
        const float* __restrict__ Wl, const float* __restrict__ Wr,
        bf16* __restrict__ wqkT, bf16* __restrict__ wlT, bf16* __restrict__ wrT) {
    int m = blockIdx.x >> 3;       // 0..2
    int chunk = blockIdx.x & 7;    // 0..7
    const float* W = (m == 0) ? Wqk : (m == 1 ? Wl : Wr);
    bf16* WT = (m == 0) ? wqkT : (m == 1 ? wlT : wrT);
#pragma unroll
    for (int e = 0; e < 8; ++e) {
        int idx = e * 256 + threadIdx.x;   // 0..2047
        int ol = idx >> 7;                 // 0..15
        int i  = idx & 127;
        int o = chunk * 16 + ol;
        WT[o * 128 + i] = (bf16)W[i * 128 + o];
    }
}

// ---------------- K1: deg = rowsum(A), pack A into bitmask ----------------
__global__ __launch_bounds__(256) void k_deg_mask(const float* __restrict__ A,
        unsigned long long* __restrict__ mask, float* __restrict__ deg) {
    const int row = blockIdx.x;              // 0..16383
    const float* a = A + (size_t)row * N_;
    const int t = threadIdx.x, w = t >> 6, lane = t & 63;
    __shared__ int partial[4];
    int cnt = 0;
    unsigned long long* mrow = mask + (size_t)row * (N_ / 64);
#pragma unroll
    for (int i = 0; i < N_ / 256; ++i) {
        float v = a[i * 256 + t];
        unsigned long long b = __ballot(v != 0.0f);
        if (lane == 0) { mrow[i * 4 + w] = b; cnt += __popcll(b); }
    }
    if (lane == 0) partial[w] = cnt;
    __syncthreads();
    if (t == 0) deg[row] = (float)(partial[0] + partial[1] + partial[2] + partial[3]);
}

// ---------------- K2: gate, xg, QK = sigmoid(xg@Wqk+bqk); write qk, xg, xgT (bf16) ----------------
__global__ __launch_bounds__(256) void k_proj(const float* __restrict__ x,
        const float* __restrict__ deg, const float* __restrict__ Wd,
        const float* __restrict__ bd, const bf16* __restrict__ wqkT,
        const float* __restrict__ bqk,
        bf16* __restrict__ qkG, bf16* __restrict__ xgG, bf16* __restrict__ xgTG) {
    __shared__ bf16 wq[128][136];
    __shared__ bf16 xgl[64][136];
    const int t = threadIdx.x, lane = t & 63, w = t >> 6;
    const int rowbase = blockIdx.x * 64;
    // stage W_qk^T (bf16, padded)
    {
        int r = t >> 1, h = t & 1;
        const bf16* src = wqkT + r * 128 + h * 64;
#pragma unroll
        for (int k = 0; k < 64; k += 8)
            *(bf16x8*)&wq[r][h * 64 + k] = *(const bf16x8*)(src + k);
    }
    // compute xg -> LDS + global
#pragma unroll
    for (int e = 0; e < 32; ++e) {
        int idx = e * 256 + t;        // 0..8191
        int rl = idx >> 7;            // 0..63
        int d  = idx & 127;
        size_t fr = (size_t)rowbase + rl;
        float g = sigmoidf_(deg[fr] * Wd[d] + bd[d]);
        float v = x[fr * 128 + d] * g;
        bf16 bv = (bf16)v;
        xgl[rl][d] = bv;
        xgG[fr * 128 + d] = bv;
    }
    __syncthreads();
    const int cIdx = lane & 15, g4 = lane >> 4;
    bf16x8 ax[4];
#pragma unroll
    for (int c = 0; c < 4; ++c)
        ax[c] = *(const bf16x8*)&xgl[w * 16 + cIdx][c * 32 + g4 * 8];
#pragma unroll
    for (int dsub = 0; dsub < 8; ++dsub) {
        f32x4 acc = {0.f, 0.f, 0.f, 0.f};
#pragma unroll
        for (int c = 0; c < 4; ++c) {
            bf16x8 bw = *(const bf16x8*)&wq[dsub * 16 + cIdx][c * 32 + g4 * 8];
            acc = __builtin_amdgcn_mfma_f32_16x16x32_bf16(ax[c], bw, acc, 0, 0, 0);
        }
        int col = dsub * 16 + cIdx;
        float bb = bqk[col];
#pragma unroll
        for (int r = 0; r < 4; ++r) {
            size_t row = (size_t)rowbase + w * 16 + g4 * 4 + r;
            qkG[row * 128 + col] = (bf16)sigmoidf_(acc[r] + bb);
        }
    }
    // xg^T write: xgT[b][d][n]
    {
        int b = rowbase / N_;
        int nbase = rowbase % N_;
#pragma unroll
        for (int e = 0; e < 32; ++e) {
            int idx = e * 256 + t;   // 0..8191
            int d  = idx >> 6;       // 0..127
            int nl = idx & 63;
            xgTG[((size_t)b * 128 + d) * N_ + nbase + nl] = xgl[nl][d];
        }
    }
}

// ---------------- K3: fused masked attention: agg = (mask*(QK QK^T)/sqrt(D)) @ xg / rowsum ----------------
__global__ __launch_bounds__(256) void k_attn(const bf16* __restrict__ qkG,
        const bf16* __restrict__ xgTG, const unsigned long long* __restrict__ maskG,
        bf16* __restrict__ aggG) {
    __shared__ bf16 qkj[128][136];
    __shared__ bf16 xgt[128][136];
    __shared__ bf16 plds[4][16][136];
    __shared__ unsigned long long ml[64][2];
    const int t = threadIdx.x, lane = t & 63, w = t >> 6;
    const int b = blockIdx.x >> 5;
    const int rowbase = (blockIdx.x & 31) * 64;
    const int cIdx = lane & 15, g4 = lane >> 4;
    const int wrow = rowbase + w * 16;
    // QK_i A-fragments (16 rows of this wave), kept in registers
    bf16x8 aq[4];
    {
        const bf16* src = qkG + ((size_t)(b * N_ + wrow + cIdx)) * 128 + g4 * 8;
#pragma unroll
        for (int c = 0; c < 4; ++c) aq[c] = *(const bf16x8*)(src + c * 32);
    }
    f32x4 num[8];
#pragma unroll
    for (int i = 0; i < 8; ++i) num[i] = {0.f, 0.f, 0.f, 0.f};
    float rs[4] = {0.f, 0.f, 0.f, 0.f};
    const float inv = 0.08838834764831845f;  // 1/sqrt(128)
    for (int j = 0; j < N_ / 128; ++j) {
        const int jbase = j * 128;
        __syncthreads();   // previous iter's LDS reads complete
        // stage QK_j, xgT tile, mask bits
        {
            int r = t >> 1, h = t & 1;
            const bf16* s1 = qkG + ((size_t)(b * N_ + jbase + r)) * 128 + h * 64;
            const bf16* s2 = xgTG + ((size_t)(b * 128 + r)) * N_ + jbase + h * 64;
#pragma unroll
            for (int k = 0; k < 64; k += 8) {
                *(bf16x8*)&qkj[r][h * 64 + k] = *(const bf16x8*)(s1 + k);
                *(bf16x8*)&xgt[r][h * 64 + k] = *(const bf16x8*)(s2 + k);
            }
            if (t < 128) {
                int rr = t >> 1, ww = t & 1;
                ml[rr][ww] = maskG[((size_t)(b * N_ + rowbase + rr)) * (N_ / 64) + jbase / 64 + ww];
            }
        }
        __syncthreads();
        // S = QK_i @ QK_j^T, then mask + scale + rowsum + P(bf16)->LDS
#pragma unroll
        for (int csub = 0; csub < 8; ++csub) {
            f32x4 s = {0.f, 0.f, 0.f, 0.f};
#pragma unroll
            for (int c = 0; c < 4; ++c) {
                bf16x8 bq = *(const bf16x8*)&qkj[csub * 16 + cIdx][c * 32 + g4 * 8];
                s = __builtin_amdgcn_mfma_f32_16x16x32_bf16(aq[c], bq, s, 0, 0, 0);
            }
#pragma unroll
            for (int r = 0; r < 4; ++r) {
                unsigned long long mw = ml[w * 16 + g4 * 4 + r][csub >> 2];
                float v = s[r] * inv;
                int bit = (csub & 3) * 16 + cIdx;
                v = ((mw >> bit) & 1ull) ? v : 0.0f;
                rs[r] += v;
                plds[w][g4 * 4 + r][csub * 16 + cIdx] = (bf16)v;
            }
        }
        __syncthreads();   // P visible to whole wave (cheap, safe)
        // num += P @ xg_j
        bf16x8 ap[4];
#pragma unroll
        for (int c = 0; c < 4; ++c)
            ap[c] = *(const bf16x8*)&plds[w][cIdx][c * 32 + g4 * 8];
#pragma unroll
        for (int dsub = 0; dsub < 8; ++dsub) {
#pragma unroll
            for (int c = 0; c < 4; ++c) {
                bf16x8 bx = *(const bf16x8*)&xgt[dsub * 16 + cIdx][c * 32 + g4 * 8];
                num[dsub] = __builtin_amdgcn_mfma_f32_16x16x32_bf16(ap[c], bx, num[dsub], 0, 0, 0);
            }
        }
    }
    // rowsum reduce across the 16 lanes of each group (cols)
#pragma unroll
    for (int r = 0; r < 4; ++r) {
        rs[r] += __shfl_xor(rs[r], 1, 64);
        rs[r] += __shfl_xor(rs[r], 2, 64);
        rs[r] += __shfl_xor(rs[r], 4, 64);
        rs[r] += __shfl_xor(rs[r], 8, 64);
    }
    float sc[4];
#pragma unroll
    for (int r = 0; r < 4; ++r) sc[r] = 1.0f / (rs[r] + 1e-6f);
#pragma unroll
    for (int dsub = 0; dsub < 8; ++dsub)
#pragma unroll
        for (int r = 0; r < 4; ++r) {
            size_t row = (size_t)b * N_ + wrow + g4 * 4 + r;
            aggG[row * 128 + dsub * 16 + cIdx] = (bf16)(num[dsub][r] * sc[r]);
        }
}

// ---------------- K4: out = normalize(agg@Wl + bl + xg@Wr) ----------------
__global__ __launch_bounds__(256) void k_out(const bf16* __restrict__ aggG,
        const bf16* __restrict__ xgG, const bf16* __restrict__ wlT,
        const bf16* __restrict__ wrT, const float* __restrict__ blv,
        float* __restrict__ out) {
    __shared__ bf16 wl[128][136];
    __shared__ bf16 wr[128][136];
    __shared__ bf16 ag[64][136];
    __shared__ bf16 xgl[64][136];
    const int t = threadIdx.x, lane = t & 63, w = t >> 6;
    const int rowbase = blockIdx.x * 64;
    {
        int r = t >> 1, h = t & 1;
#pragma unroll
        for (int k = 0; k < 64; k += 8) {
            *(bf16x8*)&wl[r][h * 64 + k] = *(const bf16x8*)(wlT + r * 128 + h * 64 + k);
            *(bf16x8*)&wr[r][h * 64 + k] = *(const bf16x8*)(wrT + r * 128 + h * 64 + k);
        }
        int rl = t >> 2, q = t & 3;
        const bf16* s1 = aggG + ((size_t)(rowbase + rl)) * 128 + q * 32;
        const bf16* s2 = xgG + ((size_t)(rowbase + rl)) * 128 + q * 32;
#pragma unroll
        for (int k = 0; k < 32; k += 8) {
            *(bf16x8*)&ag[rl][q * 32 + k] = *(const bf16x8*)(s1 + k);
            *(bf16x8*)&xgl[rl][q * 32 + k] = *(const bf16x8*)(s2 + k);
        }
    }
    __syncthreads();
    const int cIdx = lane & 15, g4 = lane >> 4;
    bf16x8 aa[4], ax[4];
#pragma unroll
    for (int c = 0; c < 4; ++c) {
        aa[c] = *(const bf16x8*)&ag[w * 16 + cIdx][c * 32 + g4 * 8];
        ax[c] = *(const bf16x8*)&xgl[w * 16 + cIdx][c * 32 + g4 * 8];
    }
    f32x4 acc[8];
    float ss[4] = {0.f, 0.f, 0.f, 0.f};
#pragma unroll
    for (int osub = 0; osub < 8; ++osub) {
        float bb = blv[osub * 16 + cIdx];
        f32x4 a = {bb, bb, bb, bb};
#pragma unroll
        for (int c = 0; c < 4; ++c) {
            bf16x8 b1 = *(const bf16x8*)&wl[osub * 16 + cIdx][c * 32 + g4 * 8];
            a = __builtin_amdgcn_mfma_f32_16x16x32_bf16(aa[c], b1, a, 0, 0, 0);
            bf16x8 b2 = *(const bf16x8*)&wr[osub * 16 + cIdx][c * 32 + g4 * 8];
            a = __builtin_amdgcn_mfma_f32_16x16x32_bf16(ax[c], b2, a, 0, 0, 0);
        }
        acc[osub] = a;
#pragma unroll
        for (int r = 0; r < 4; ++r) ss[r] += a[r] * a[r];
    }
#pragma unroll
    for (int r = 0; r < 4; ++r) {
        ss[r] += __shfl_xor(ss[r], 1, 64);
        ss[r] += __shfl_xor(ss[r], 2, 64);
        ss[r] += __shfl_xor(ss[r], 4, 64);
        ss[r] += __shfl_xor(ss[r], 8, 64);
    }
    float sc[4];
#pragma unroll
    for (int r = 0; r < 4; ++r) sc[r] = 1.0f / fmaxf(sqrtf(ss[r]), 1e-12f);
#pragma unroll
    for (int osub = 0; osub < 8; ++osub)
#pragma unroll
        for (int r = 0; r < 4; ++r) {
            size_t row = (size_t)rowbase + w * 16 + g4 * 4 + r;
            out[row * 128 + osub * 16 + cIdx] = acc[osub][r] * sc[r];
        }
}

extern "C" void kernel_launch(void* const* d_in, const int* in_sizes, int n_in,
                              void* d_out, int out_size, void* d_ws, size_t ws_size,
                              hipStream_t stream) {
    const float* x   = (const float*)d_in[0];
    const float* A   = (const float*)d_in[1];
    const float* Wqk = (const float*)d_in[2];
    const float* bqk = (const float*)d_in[3];
    const float* Wl  = (const float*)d_in[4];
    const float* bl  = (const float*)d_in[5];
    const float* Wr  = (const float*)d_in[6];
    const float* Wd  = (const float*)d_in[7];
    const float* bd  = (const float*)d_in[8];
    float* out = (float*)d_out;
    char* ws = (char*)d_ws;

    unsigned long long* maskG = (unsigned long long*)ws;          // 4 MB
    float* degG = (float*)(ws + (4 << 20));                       // 64 KB
    bf16* wqkT  = (bf16*)(ws + (5 << 20));                        // 32 KB
    bf16* wlT   = (bf16*)(ws + (5 << 20) + 32768);
    bf16* wrT   = (bf16*)(ws + (5 << 20) + 65536);
    bf16* qkG   = (bf16*)(ws + (6 << 20));                        // 4 MB
    bf16* xgG   = (bf16*)(ws + (10 << 20));                       // 4 MB
    bf16* xgTG  = (bf16*)(ws + (14 << 20));                       // 4 MB
    bf16* aggG  = (bf16*)(ws + (18 << 20));                       // 4 MB

    hipLaunchKernelGGL(k_wtrans, dim3(24), dim3(256), 0, stream, Wqk, Wl, Wr, wqkT, wlT, wrT);
    hipLaunchKernelGGL(k_deg_mask, dim3(NROW), dim3(256), 0, stream, A, maskG, degG);
    hipLaunchKernelGGL(k_proj, dim3(NROW / 64), dim3(256), 0, stream,
                       x, degG, Wd, bd, wqkT, bqk, qkG, xgG, xgTG);
    hipLaunchKernelGGL(k_attn, dim3(NROW / 64), dim3(256), 0, stream, qkG, xgTG, maskG, aggG);
    hipLaunchKernelGGL(k_out, dim3(NROW / 64), dim3(256), 0, stream, aggG, xgG, wlT, wrT, bl, out);
}

// Round 2
// 262.219 us; speedup vs baseline: 1.1633x; 1.1633x over previous
//
#include <hip/hip_runtime.h>
#include <hip/hip_bf16.h>

#define B_ 8
#define N_ 2048
#define D_ 128
#define NROW (B_*N_)   // 16384

typedef __bf16 bf16;
typedef __bf16 bf16x8 __attribute__((ext_vector_type(8)));
typedef float f32x4 __attribute__((ext_vector_type(4)));

__device__ __forceinline__ float sigmoidf_(float x) {
    return 1.0f / (1.0f + __expf(-x));
}

__device__ __forceinline__ void g2l16(const bf16* g, void* l) {
    __builtin_amdgcn_global_load_lds(
        (const __attribute__((address_space(1))) unsigned int*)g,
        (__attribute__((address_space(3))) unsigned int*)l, 16, 0, 0);
}

// ---------------- K0: transpose W_qk, W_l, W_r -> bf16 [out][in] ----------------
__global__ __launch_bounds__(256) void k_wtrans(const float* __restrict__ Wqk,
        const float* __restrict__ Wl, const float* __restrict__ Wr,
        bf16* __restrict__ wqkT, bf16* __restrict__ wlT, bf16* __restrict__ wrT) {
    int m = blockIdx.x >> 3;       // 0..2
    int chunk = blockIdx.x & 7;    // 0..7
    const float* W = (m == 0) ? Wqk : (m == 1 ? Wl : Wr);
    bf16* WT = (m == 0) ? wqkT : (m == 1 ? wlT : wrT);
#pragma unroll
    for (int e = 0; e < 8; ++e) {
        int idx = e * 256 + threadIdx.x;   // 0..2047
        int ol = idx >> 7;                 // 0..15
        int i  = idx & 127;
        int o = chunk * 16 + ol;
        WT[o * 128 + i] = (bf16)W[i * 128 + o];
    }
}

// ---------------- K1: deg = rowsum(A), pack A into u32 bitmask (float4 loads) ----------------
__global__ __launch_bounds__(256) void k_deg_mask(const float* __restrict__ A,
        unsigned int* __restrict__ mask, float* __restrict__ deg) {
    const int row = blockIdx.x;              // 0..16383
    const float* a = A + (size_t)row * N_;
    const int t = threadIdx.x, w = t >> 6, lane = t & 63;
    __shared__ int partial[4];
    int cnt = 0;
    unsigned int* mrow = mask + (size_t)row * (N_ / 32);
#pragma unroll
    for (int i = 0; i < N_ / 1024; ++i) {
        float4 v = *(const float4*)(a + i * 1024 + t * 4);
        unsigned long long nib = (unsigned long long)((v.x != 0.f) | ((v.y != 0.f) << 1) |
                                                      ((v.z != 0.f) << 2) | ((v.w != 0.f) << 3));
        unsigned long long p = nib << ((t & 15) * 4);
        p |= __shfl_xor(p, 1);
        p |= __shfl_xor(p, 2);
        p |= __shfl_xor(p, 4);
        p |= __shfl_xor(p, 8);
        if ((t & 15) == 0) {
            int idx = i * 32 + (t >> 4) * 2;
            mrow[idx] = (unsigned int)p;
            mrow[idx + 1] = (unsigned int)(p >> 32);
            cnt += __popcll(p);
        }
    }
    cnt += __shfl_xor(cnt, 16);
    cnt += __shfl_xor(cnt, 32);
    if (lane == 0) partial[w] = cnt;
    __syncthreads();
    if (t == 0) deg[row] = (float)(partial[0] + partial[1] + partial[2] + partial[3]);
}

// ---------------- K2: gate, xg, QK = sigmoid(xg@Wqk+bqk); write qk, xg, xgT (bf16) ----------------
__global__ __launch_bounds__(256) void k_proj(const float* __restrict__ x,
        const float* __restrict__ deg, const float* __restrict__ Wd,
        const float* __restrict__ bd, const bf16* __restrict__ wqkT,
        const float* __restrict__ bqk,
        bf16* __restrict__ qkG, bf16* __restrict__ xgG, bf16* __restrict__ xgTG) {
    __shared__ bf16 wq[128][136];
    __shared__ bf16 xgl[64][136];
    const int t = threadIdx.x, lane = t & 63, w = t >> 6;
    const int rowbase = blockIdx.x * 64;
    {
        int r = t >> 1, h = t & 1;
        const bf16* src = wqkT + r * 128 + h * 64;
#pragma unroll
        for (int k = 0; k < 64; k += 8)
            *(bf16x8*)&wq[r][h * 64 + k] = *(const bf16x8*)(src + k);
    }
#pragma unroll
    for (int e = 0; e < 32; ++e) {
        int idx = e * 256 + t;        // 0..8191
        int rl = idx >> 7;            // 0..63
        int d  = idx & 127;
        size_t fr = (size_t)rowbase + rl;
        float g = sigmoidf_(deg[fr] * Wd[d] + bd[d]);
        float v = x[fr * 128 + d] * g;
        bf16 bv = (bf16)v;
        xgl[rl][d] = bv;
        xgG[fr * 128 + d] = bv;
    }
    __syncthreads();
    const int cIdx = lane & 15, g4 = lane >> 4;
    bf16x8 ax[4];
#pragma unroll
    for (int c = 0; c < 4; ++c)
        ax[c] = *(const bf16x8*)&xgl[w * 16 + cIdx][c * 32 + g4 * 8];
#pragma unroll
    for (int dsub = 0; dsub < 8; ++dsub) {
        f32x4 acc = {0.f, 0.f, 0.f, 0.f};
#pragma unroll
        for (int c = 0; c < 4; ++c) {
            bf16x8 bw = *(const bf16x8*)&wq[dsub * 16 + cIdx][c * 32 + g4 * 8];
            acc = __builtin_amdgcn_mfma_f32_16x16x32_bf16(ax[c], bw, acc, 0, 0, 0);
        }
        int col = dsub * 16 + cIdx;
        float bb = bqk[col];
#pragma unroll
        for (int r = 0; r < 4; ++r) {
            size_t row = (size_t)rowbase + w * 16 + g4 * 4 + r;
            qkG[row * 128 + col] = (bf16)sigmoidf_(acc[r] + bb);
        }
    }
    {
        int b = rowbase / N_;
        int nbase = rowbase % N_;
#pragma unroll
        for (int e = 0; e < 32; ++e) {
            int idx = e * 256 + t;   // 0..8191
            int d  = idx >> 6;       // 0..127
            int nl = idx & 63;
            xgTG[((size_t)b * 128 + d) * N_ + nbase + nl] = xgl[nl][d];
        }
    }
}

// ---------------- K3: fused masked attention (8 waves, 4 j-quarters, dbuf + gload_lds + swizzle) ----------------
// LDS layout (bytes):
//   [0,      65536)  QKJ[buf2][quarter4][32 jrow][128 d]  (swizzled, 8KB tiles)
//   [65536, 131072)  XGT[buf2][quarter4][128 d][32 j]     (swizzled, 8KB tiles)
//   [131072,147456)  PLDS[8 waves][32][32]                (swizzled P tiles)
//   [147456,148480)  RSB[64 rows][4 quarters] f32
//   epilogue: PART[4 q][64 row][128 col] f32 aliases [0,131072)
__global__ __launch_bounds__(512, 2) void k_attn(const bf16* __restrict__ qkG,
        const bf16* __restrict__ xgTG, const unsigned int* __restrict__ mask32,
        bf16* __restrict__ aggG) {
    __shared__ __align__(16) char LDSC[148480];
    const int t = threadIdx.x, lane = t & 63, w = t >> 6;
    const int q = w >> 1, s = w & 1;          // compute quarter, row-half
    const int cIdx = lane & 15, g4 = lane >> 4;
    const int bid = (blockIdx.x & 7) * 32 + (blockIdx.x >> 3);   // XCD swizzle (bijective, 256%8==0)
    const int b = bid >> 5;
    const int rowbase = (bid & 31) * 64;
    const int R0 = rowbase + s * 32;

    const int sq = w & 3;                      // quarter this wave STAGES
    const bool stq = (w < 4);                  // true: stage QKJ, false: stage XGT

    auto do_stage = [&](int ts, int bbuf) {
        const int jbase = sq * 512 + ts * 32;
        if (stq) {
            const int rowi = lane >> 4;        // 0..3
            const int g = lane & 15;
#pragma unroll
            for (int i = 0; i < 8; ++i) {
                int row = i * 4 + rowi;        // j-local 0..31
                const bf16* gsrc = qkG + ((size_t)(b * N_ + jbase + row)) * 128 + ((g ^ (row & 7)) << 3);
                g2l16(gsrc, LDSC + (bbuf * 4 + sq) * 8192 + i * 1024);
            }
        } else {
            const int di = lane >> 2;          // 0..15
            const int g = lane & 3;
#pragma unroll
            for (int i = 0; i < 8; ++i) {
                int d = i * 16 + di;           // 0..127
                const bf16* gsrc = xgTG + ((size_t)(b * 128 + d)) * N_ + jbase + ((g ^ ((d >> 2) & 3)) << 3);
                g2l16(gsrc, LDSC + 65536 + (bbuf * 4 + sq) * 8192 + i * 1024);
            }
        }
    };

    // A fragments: this wave's 32 i-rows (2 subtiles of 16)
    bf16x8 aq[2][4];
#pragma unroll
    for (int isub = 0; isub < 2; ++isub) {
        const bf16* src = qkG + ((size_t)(b * N_ + R0 + isub * 16 + cIdx)) * 128 + g4 * 8;
#pragma unroll
        for (int kc = 0; kc < 4; ++kc) aq[isub][kc] = *(const bf16x8*)(src + kc * 32);
    }
    // mask word prefetch: lane l<32 holds row_local=l's u32 for current step
    const unsigned int* mrow = mask32 + ((size_t)(b * N_ + R0 + (lane & 31))) * (N_ / 32) + q * 16;
    unsigned int mw_cur = (lane < 32) ? mrow[0] : 0u;

    do_stage(0, 0);
    __syncthreads();

    f32x4 num[2][8];
#pragma unroll
    for (int i = 0; i < 2; ++i)
#pragma unroll
        for (int jd = 0; jd < 8; ++jd) num[i][jd] = {0.f, 0.f, 0.f, 0.f};
    float rs[2][4] = {{0.f, 0.f, 0.f, 0.f}, {0.f, 0.f, 0.f, 0.f}};
    const float inv = 0.08838834764831845f;  // 1/sqrt(128)

    for (int ts = 0; ts < 16; ++ts) {
        const int bb = ts & 1;
        unsigned int mw_nxt = 0;
        if (ts < 15) {
            mw_nxt = (lane < 32) ? mrow[ts + 1] : 0u;
            do_stage(ts + 1, bb ^ 1);
        }
        // ---- S = QK_i @ QK_j^T for this quarter's 32-wide j window
        const char* qb = LDSC + (bb * 4 + q) * 8192;
        f32x4 sv[2][2];
#pragma unroll
        for (int i = 0; i < 2; ++i) { sv[i][0] = {0.f,0.f,0.f,0.f}; sv[i][1] = {0.f,0.f,0.f,0.f}; }
#pragma unroll
        for (int kc = 0; kc < 4; ++kc) {
#pragma unroll
            for (int csub = 0; csub < 2; ++csub) {
                int jl = csub * 16 + cIdx;
                bf16x8 bq = *(const bf16x8*)(qb + jl * 256 + ((((kc << 2) | g4) ^ (jl & 7)) << 4));
                sv[0][csub] = __builtin_amdgcn_mfma_f32_16x16x32_bf16(aq[0][kc], bq, sv[0][csub], 0, 0, 0);
                sv[1][csub] = __builtin_amdgcn_mfma_f32_16x16x32_bf16(aq[1][kc], bq, sv[1][csub], 0, 0, 0);
            }
        }
        // ---- mask + scale + rowsum + P(bf16) -> wave-private swizzled LDS
        char* pb = LDSC + 131072 + w * 2048;
#pragma unroll
        for (int isub = 0; isub < 2; ++isub)
#pragma unroll
        for (int r = 0; r < 4; ++r) {
            int rl = isub * 16 + g4 * 4 + r;               // wave-local row 0..31
            unsigned int mwv = __shfl(mw_cur, rl);
#pragma unroll
            for (int csub = 0; csub < 2; ++csub) {
                float v = sv[isub][csub][r] * inv;
                v = ((mwv >> (csub * 16 + cIdx)) & 1u) ? v : 0.0f;
                rs[isub][r] += v;
                *(bf16*)(pb + rl * 64 + ((((csub << 1) | (cIdx >> 3)) ^ ((rl >> 2) & 3)) << 4)
                         + ((cIdx & 7) << 1)) = (bf16)v;
            }
        }
        // ---- num += P @ xg_j
        const char* xb = LDSC + 65536 + (bb * 4 + q) * 8192;
        bf16x8 ap[2];
#pragma unroll
        for (int isub = 0; isub < 2; ++isub) {
            int rl = isub * 16 + cIdx;
            ap[isub] = *(const bf16x8*)(pb + rl * 64 + ((g4 ^ ((rl >> 2) & 3)) << 4));
        }
#pragma unroll
        for (int dsub = 0; dsub < 8; ++dsub) {
            int d = dsub * 16 + cIdx;
            bf16x8 bx = *(const bf16x8*)(xb + d * 64 + ((g4 ^ ((d >> 2) & 3)) << 4));
            num[0][dsub] = __builtin_amdgcn_mfma_f32_16x16x32_bf16(ap[0], bx, num[0][dsub], 0, 0, 0);
            num[1][dsub] = __builtin_amdgcn_mfma_f32_16x16x32_bf16(ap[1], bx, num[1][dsub], 0, 0, 0);
        }
        mw_cur = mw_nxt;
        __syncthreads();   // drains staged loads; next buffer ready; tiles free to overwrite
    }

    // ---- epilogue: combine the 4 quarter-partials per row
#pragma unroll
    for (int isub = 0; isub < 2; ++isub)
#pragma unroll
    for (int r = 0; r < 4; ++r) {
        float v = rs[isub][r];
        v += __shfl_xor(v, 1); v += __shfl_xor(v, 2); v += __shfl_xor(v, 4); v += __shfl_xor(v, 8);
        rs[isub][r] = v;
    }
    float* RSB = (float*)(LDSC + 147456);
    if (cIdx == 0) {
#pragma unroll
        for (int isub = 0; isub < 2; ++isub)
#pragma unroll
        for (int r = 0; r < 4; ++r)
            RSB[(s * 32 + isub * 16 + g4 * 4 + r) * 4 + q] = rs[isub][r];
    }
    float* PART = (float*)LDSC;   // aliases tile buffers (dead now)
#pragma unroll
    for (int isub = 0; isub < 2; ++isub)
#pragma unroll
    for (int dsub = 0; dsub < 8; ++dsub)
#pragma unroll
    for (int r = 0; r < 4; ++r)
        PART[q * 8192 + (s * 32 + isub * 16 + g4 * 4 + r) * 128 + dsub * 16 + cIdx] = num[isub][dsub][r];
    __syncthreads();
    {
        int row = t >> 3, colbase = (t & 7) * 16;
        float accv[16];
#pragma unroll
        for (int k = 0; k < 16; ++k) accv[k] = 0.f;
#pragma unroll
        for (int q4 = 0; q4 < 4; ++q4)
#pragma unroll
            for (int k = 0; k < 4; ++k) {
                f32x4 pv = *(const f32x4*)(PART + q4 * 8192 + row * 128 + colbase + k * 4);
                accv[k * 4 + 0] += pv[0]; accv[k * 4 + 1] += pv[1];
                accv[k * 4 + 2] += pv[2]; accv[k * 4 + 3] += pv[3];
            }
        float den = RSB[row * 4 + 0] + RSB[row * 4 + 1] + RSB[row * 4 + 2] + RSB[row * 4 + 3] + 1e-6f;
        float sc = 1.0f / den;
        bf16x8 o0, o1;
#pragma unroll
        for (int k = 0; k < 8; ++k) { o0[k] = (bf16)(accv[k] * sc); o1[k] = (bf16)(accv[8 + k] * sc); }
        bf16* dst = aggG + ((size_t)(b * N_ + rowbase + row)) * 128 + colbase;
        *(bf16x8*)dst = o0;
        *(bf16x8*)(dst + 8) = o1;
    }
}

// ---------------- K4: out = normalize(agg@Wl + bl + xg@Wr) ----------------
__global__ __launch_bounds__(256) void k_out(const bf16* __restrict__ aggG,
        const bf16* __restrict__ xgG, const bf16* __restrict__ wlT,
        const bf16* __restrict__ wrT, const float* __restrict__ blv,
        float* __restrict__ out) {
    __shared__ bf16 wl[128][136];
    __shared__ bf16 wr[128][136];
    __shared__ bf16 ag[64][136];
    __shared__ bf16 xgl[64][136];
    const int t = threadIdx.x, lane = t & 63, w = t >> 6;
    const int rowbase = blockIdx.x * 64;
    {
        int r = t >> 1, h = t & 1;
#pragma unroll
        for (int k = 0; k < 64; k += 8) {
            *(bf16x8*)&wl[r][h * 64 + k] = *(const bf16x8*)(wlT + r * 128 + h * 64 + k);
            *(bf16x8*)&wr[r][h * 64 + k] = *(const bf16x8*)(wrT + r * 128 + h * 64 + k);
        }
        int rl = t >> 2, q = t & 3;
        const bf16* s1 = aggG + ((size_t)(rowbase + rl)) * 128 + q * 32;
        const bf16* s2 = xgG + ((size_t)(rowbase + rl)) * 128 + q * 32;
#pragma unroll
        for (int k = 0; k < 32; k += 8) {
            *(bf16x8*)&ag[rl][q * 32 + k] = *(const bf16x8*)(s1 + k);
            *(bf16x8*)&xgl[rl][q * 32 + k] = *(const bf16x8*)(s2 + k);
        }
    }
    __syncthreads();
    const int cIdx = lane & 15, g4 = lane >> 4;
    bf16x8 aa[4], ax[4];
#pragma unroll
    for (int c = 0; c < 4; ++c) {
        aa[c] = *(const bf16x8*)&ag[w * 16 + cIdx][c * 32 + g4 * 8];
        ax[c] = *(const bf16x8*)&xgl[w * 16 + cIdx][c * 32 + g4 * 8];
    }
    f32x4 acc[8];
    float ss[4] = {0.f, 0.f, 0.f, 0.f};
#pragma unroll
    for (int osub = 0; osub < 8; ++osub) {
        float bb = blv[osub * 16 + cIdx];
        f32x4 a = {bb, bb, bb, bb};
#pragma unroll
        for (int c = 0; c < 4; ++c) {
            bf16x8 b1 = *(const bf16x8*)&wl[osub * 16 + cIdx][c * 32 + g4 * 8];
            a = __builtin_amdgcn_mfma_f32_16x16x32_bf16(aa[c], b1, a, 0, 0, 0);
            bf16x8 b2 = *(const bf16x8*)&wr[osub * 16 + cIdx][c * 32 + g4 * 8];
            a = __builtin_amdgcn_mfma_f32_16x16x32_bf16(ax[c], b2, a, 0, 0, 0);
        }
        acc[osub] = a;
#pragma unroll
        for (int r = 0; r < 4; ++r) ss[r] += a[r] * a[r];
    }
#pragma unroll
    for (int r = 0; r < 4; ++r) {
        ss[r] += __shfl_xor(ss[r], 1);
        ss[r] += __shfl_xor(ss[r], 2);
        ss[r] += __shfl_xor(ss[r], 4);
        ss[r] += __shfl_xor(ss[r], 8);
    }
    float sc[4];
#pragma unroll
    for (int r = 0; r < 4; ++r) sc[r] = 1.0f / fmaxf(sqrtf(ss[r]), 1e-12f);
#pragma unroll
    for (int osub = 0; osub < 8; ++osub)
#pragma unroll
        for (int r = 0; r < 4; ++r) {
            size_t row = (size_t)rowbase + w * 16 + g4 * 4 + r;
            out[row * 128 + osub * 16 + cIdx] = acc[osub][r] * sc[r];
        }
}

extern "C" void kernel_launch(void* const* d_in, const int* in_sizes, int n_in,
                              void* d_out, int out_size, void* d_ws, size_t ws_size,
                              hipStream_t stream) {
    const float* x   = (const float*)d_in[0];
    const float* A   = (const float*)d_in[1];
    const float* Wqk = (const float*)d_in[2];
    const float* bqk = (const float*)d_in[3];
    const float* Wl  = (const float*)d_in[4];
    const float* bl  = (const float*)d_in[5];
    const float* Wr  = (const float*)d_in[6];
    const float* Wd  = (const float*)d_in[7];
    const float* bd  = (const float*)d_in[8];
    float* out = (float*)d_out;
    char* ws = (char*)d_ws;

    unsigned int* maskG = (unsigned int*)ws;                      // 4 MB
    float* degG = (float*)(ws + (4 << 20));                       // 64 KB
    bf16* wqkT  = (bf16*)(ws + (5 << 20));                        // 32 KB
    bf16* wlT   = (bf16*)(ws + (5 << 20) + 32768);
    bf16* wrT   = (bf16*)(ws + (5 << 20) + 65536);
    bf16* qkG   = (bf16*)(ws + (6 << 20));                        // 4 MB
    bf16* xgG   = (bf16*)(ws + (10 << 20));                       // 4 MB
    bf16* xgTG  = (bf16*)(ws + (14 << 20));                       // 4 MB
    bf16* aggG  = (bf16*)(ws + (18 << 20));                       // 4 MB

    hipLaunchKernelGGL(k_wtrans, dim3(24), dim3(256), 0, stream, Wqk, Wl, Wr, wqkT, wlT, wrT);
    hipLaunchKernelGGL(k_deg_mask, dim3(NROW), dim3(256), 0, stream, A, maskG, degG);
    hipLaunchKernelGGL(k_proj, dim3(NROW / 64), dim3(256), 0, stream,
                       x, degG, Wd, bd, wqkT, bqk, qkG, xgG, xgTG);
    hipLaunchKernelGGL(k_attn, dim3(NROW / 64), dim3(512), 0, stream, qkG, xgTG, maskG, aggG);
    hipLaunchKernelGGL(k_out, dim3(NROW / 64), dim3(256), 0, stream, aggG, xgG, wlT, wrT, bl, out);
}

// Round 4
// 255.216 us; speedup vs baseline: 1.1952x; 1.0274x over previous
//
#include <hip/hip_runtime.h>
#include <hip/hip_bf16.h>

#define B_ 8
#define N_ 2048
#define D_ 128
#define NROW (B_*N_)   // 16384

typedef __bf16 bf16;
typedef __bf16 bf16x8 __attribute__((ext_vector_type(8)));
typedef float f32x4 __attribute__((ext_vector_type(4)));
typedef float f32x16 __attribute__((ext_vector_type(16)));

__device__ __forceinline__ float sigmoidf_(float x) {
    return 1.0f / (1.0f + __expf(-x));
}

__device__ __forceinline__ void g2l16(const bf16* g, void* l) {
    __builtin_amdgcn_global_load_lds(
        (const __attribute__((address_space(1))) unsigned int*)g,
        (__attribute__((address_space(3))) unsigned int*)l, 16, 0, 0);
}

__device__ __forceinline__ unsigned pk_bf16(float a, float b) {
    union { bf16 h[2]; unsigned u; } t;
    t.h[0] = (bf16)a; t.h[1] = (bf16)b;
    return t.u;
}

// ---------------- K0: transpose W_qk, W_l, W_r -> bf16 [out][in] ----------------
__global__ __launch_bounds__(256) void k_wtrans(const float* __restrict__ Wqk,
        const float* __restrict__ Wl, const float* __restrict__ Wr,
        bf16* __restrict__ wqkT, bf16* __restrict__ wlT, bf16* __restrict__ wrT) {
    int m = blockIdx.x >> 3;       // 0..2
    int chunk = blockIdx.x & 7;    // 0..7
    const float* W = (m == 0) ? Wqk : (m == 1 ? Wl : Wr);
    bf16* WT = (m == 0) ? wqkT : (m == 1 ? wlT : wrT);
#pragma unroll
    for (int e = 0; e < 8; ++e) {
        int idx = e * 256 + threadIdx.x;   // 0..2047
        int ol = idx >> 7;                 // 0..15
        int i  = idx & 127;
        int o = chunk * 16 + ol;
        WT[o * 128 + i] = (bf16)W[i * 128 + o];
    }
}

// ---------------- K1: deg = rowsum(A), pack A into u32 bitmask (float4 loads) ----------------
__global__ __launch_bounds__(256) void k_deg_mask(const float* __restrict__ A,
        unsigned int* __restrict__ mask, float* __restrict__ deg) {
    const int row = blockIdx.x;              // 0..16383
    const float* a = A + (size_t)row * N_;
    const int t = threadIdx.x, w = t >> 6, lane = t & 63;
    __shared__ int partial[4];
    int cnt = 0;
    unsigned int* mrow = mask + (size_t)row * (N_ / 32);
#pragma unroll
    for (int i = 0; i < N_ / 1024; ++i) {
        float4 v = *(const float4*)(a + i * 1024 + t * 4);
        unsigned long long nib = (unsigned long long)((v.x != 0.f) | ((v.y != 0.f) << 1) |
                                                      ((v.z != 0.f) << 2) | ((v.w != 0.f) << 3));
        unsigned long long p = nib << ((t & 15) * 4);
        p |= __shfl_xor(p, 1);
        p |= __shfl_xor(p, 2);
        p |= __shfl_xor(p, 4);
        p |= __shfl_xor(p, 8);
        if ((t & 15) == 0) {
            int idx = i * 32 + (t >> 4) * 2;
            mrow[idx] = (unsigned int)p;
            mrow[idx + 1] = (unsigned int)(p >> 32);
            cnt += __popcll(p);
        }
    }
    cnt += __shfl_xor(cnt, 16);
    cnt += __shfl_xor(cnt, 32);
    if (lane == 0) partial[w] = cnt;
    __syncthreads();
    if (t == 0) deg[row] = (float)(partial[0] + partial[1] + partial[2] + partial[3]);
}

// ---------------- K2: gate, xg, QK = sigmoid(xg@Wqk+bqk); write qk, xg, xgT (bf16) ----------------
__global__ __launch_bounds__(256) void k_proj(const float* __restrict__ x,
        const float* __restrict__ deg, const float* __restrict__ Wd,
        const float* __restrict__ bd, const bf16* __restrict__ wqkT,
        const float* __restrict__ bqk,
        bf16* __restrict__ qkG, bf16* __restrict__ xgG, bf16* __restrict__ xgTG) {
    __shared__ bf16 wq[128][136];
    __shared__ bf16 xgl[64][136];
    const int t = threadIdx.x, lane = t & 63, w = t >> 6;
    const int rowbase = blockIdx.x * 64;
    {
        int r = t >> 1, h = t & 1;
        const bf16* src = wqkT + r * 128 + h * 64;
#pragma unroll
        for (int k = 0; k < 64; k += 8)
            *(bf16x8*)&wq[r][h * 64 + k] = *(const bf16x8*)(src + k);
    }
#pragma unroll
    for (int e = 0; e < 32; ++e) {
        int idx = e * 256 + t;        // 0..8191
        int rl = idx >> 7;            // 0..63
        int d  = idx & 127;
        size_t fr = (size_t)rowbase + rl;
        float g = sigmoidf_(deg[fr] * Wd[d] + bd[d]);
        float v = x[fr * 128 + d] * g;
        bf16 bv = (bf16)v;
        xgl[rl][d] = bv;
        xgG[fr * 128 + d] = bv;
    }
    __syncthreads();
    const int cIdx = lane & 15, g4 = lane >> 4;
    bf16x8 ax[4];
#pragma unroll
    for (int c = 0; c < 4; ++c)
        ax[c] = *(const bf16x8*)&xgl[w * 16 + cIdx][c * 32 + g4 * 8];
#pragma unroll
    for (int dsub = 0; dsub < 8; ++dsub) {
        f32x4 acc = {0.f, 0.f, 0.f, 0.f};
#pragma unroll
        for (int c = 0; c < 4; ++c) {
            bf16x8 bw = *(const bf16x8*)&wq[dsub * 16 + cIdx][c * 32 + g4 * 8];
            acc = __builtin_amdgcn_mfma_f32_16x16x32_bf16(ax[c], bw, acc, 0, 0, 0);
        }
        int col = dsub * 16 + cIdx;
        float bb = bqk[col];
#pragma unroll
        for (int r = 0; r < 4; ++r) {
            size_t row = (size_t)rowbase + w * 16 + g4 * 4 + r;
            qkG[row * 128 + col] = (bf16)sigmoidf_(acc[r] + bb);
        }
    }
    {
        int b = rowbase / N_;
        int nbase = rowbase % N_;
#pragma unroll
        for (int e = 0; e < 32; ++e) {
            int idx = e * 256 + t;   // 0..8191
            int d  = idx >> 6;       // 0..127
            int nl = idx & 63;
            xgTG[((size_t)b * 128 + d) * N_ + nbase + nl] = xgl[nl][d];
        }
    }
}

// ---------------- K3: fused masked attention, 32x32 MFMA, in-register P ----------------
// Block: 64 i-rows, 512 threads = 8 waves = 2 i-halves (s) x 4 j-quarters (q).
// S^T = mfma(A=QK_j(LDS), B=QK_i(reg)) -> lane holds P[.][i=l31] for 16 j's.
// P stays in C-layout registers; PV loads B j-matched to J(h,e)=4h+(e&3)+8*(e>>2)
// so NO cross-lane movement is needed.
// LDS:
//   [0,      65536)  QKJ dbuf: [buf2][128 j][16 granules of 16B]  (granule ^ (j&7))
//   [65536, 131072)  XGT dbuf: [buf2][128 d][16 granules]         (granule ^ (d&7))
//   [131072,132096)  RSB[64 rows][4 quarters] f32
//   epilogue: PART[4 q][64 i][128 d] f32 aliases [0,131072)
__global__ __launch_bounds__(512, 2) void k_attn(const bf16* __restrict__ qkG,
        const bf16* __restrict__ xgTG, const unsigned int* __restrict__ mask32,
        bf16* __restrict__ aggG) {
    __shared__ __align__(16) char LDSC[132096];
    const int t = threadIdx.x, l = t & 63, w = t >> 6;
    const int h = l >> 5, l31 = l & 31;
    const int q = w >> 1, s = w & 1;
    const int bid = (blockIdx.x & 7) * 32 + (blockIdx.x >> 3);   // XCD swizzle (bijective)
    const int b = bid >> 5;
    const int rowbase = (bid & 31) * 64;
    const int R0 = rowbase + s * 32;
    const float inv = 0.08838834764831845f;  // 1/sqrt(128)

    // staging: wave w handles rows w*16..w*16+15 of both tiles
    auto do_stage = [&](int jb, int bbuf) {
        char* qdst = LDSC + bbuf * 32768 + w * 4096;
        char* xdst = LDSC + 65536 + bbuf * 32768 + w * 4096;
#pragma unroll
        for (int i = 0; i < 4; ++i) {
            int G = w * 256 + i * 64 + l;
            int j = G >> 4, g = G & 15;
            const bf16* src = qkG + ((size_t)(b * N_ + jb + j)) * 128 + ((g ^ (j & 7)) << 3);
            g2l16(src, qdst + i * 1024);
            const bf16* src2 = xgTG + ((size_t)b * 128 + j) * N_ + jb + ((g ^ (j & 7)) << 3);
            g2l16(src2, xdst + i * 1024);
        }
    };

    // QK_i B-fragments: lane holds col i = R0+l31, k = d (8 per slice), 8 slices
    bf16x8 qki[8];
    {
        const bf16* srcB = qkG + ((size_t)(b * N_ + R0 + l31)) * 128 + h * 8;
#pragma unroll
        for (int sl = 0; sl < 8; ++sl) qki[sl] = *(const bf16x8*)(srcB + sl * 16);
    }
    // mask: per-lane own-row word for current 32-j window
    const unsigned int* mrow = mask32 + ((size_t)(b * N_ + R0 + l31)) * (N_ / 32) + q;
    unsigned int mw = mrow[0];

    do_stage(0, 0);
    __syncthreads();

    f32x16 num[4]; num[0] = f32x16{}; num[1] = f32x16{}; num[2] = f32x16{}; num[3] = f32x16{};
    float rs = 0.f;

    for (int ts = 0; ts < 16; ++ts) {
        const int bb = ts & 1;
        unsigned int mw_n = 0;
        if (ts < 15) {
            mw_n = mrow[(ts + 1) * 4];
            do_stage((ts + 1) * 128, bb ^ 1);
        }
        const char* qb = LDSC + bb * 32768;
        const char* xb = LDSC + 65536 + bb * 32768;
        // ---- S^T = QK_j @ QK_i^T  (rows j, cols i)
        f32x16 st{};
        const int rowb = (q * 32 + l31) * 256;
#pragma unroll
        for (int sl = 0; sl < 8; ++sl) {
            bf16x8 aj = *(const bf16x8*)(qb + rowb + ((((sl << 1) | h) ^ (l & 7)) << 4));
            st = __builtin_amdgcn_mfma_f32_32x32x16_bf16(aj, qki[sl], st, 0, 0, 0);
        }
        // ---- mask + scale + rowsum + pack to bf16 pairs (C-layout order)
        unsigned int mws = mw >> (h * 4);
        unsigned int wpk[8];
#pragma unroll
        for (int r2 = 0; r2 < 8; ++r2) {
            const int r = r2 * 2;
            const int bit0 = (r & 3) + 8 * (r >> 2);
            float p0 = ((mws >> bit0) & 1u) ? st[r] * inv : 0.f;
            float p1 = ((mws >> (bit0 + 1)) & 1u) ? st[r + 1] * inv : 0.f;
            rs += p0 + p1;
            wpk[r2] = pk_bf16(p0, p1);
        }
        // ---- PV A-fragments = P as-is (C-layout); element e of half h holds
        //      j = J(h,e) = 4h + (e&3) + 8*(e>>2)  (+16 for pa1)
        union { unsigned int u[4]; bf16x8 v; } pa0, pa1;
        pa0.u[0] = wpk[0]; pa0.u[1] = wpk[1]; pa0.u[2] = wpk[2]; pa0.u[3] = wpk[3];
        pa1.u[0] = wpk[4]; pa1.u[1] = wpk[5]; pa1.u[2] = wpk[6]; pa1.u[3] = wpk[7];
        // ---- num += P @ xg_j : B loaded j-matched to J(h,e)
        const int xr = l & 7;
#pragma unroll
        for (int c = 0; c < 4; ++c) {
            const char* rowp = xb + (c * 32 + l31) * 256;
            union { unsigned long long d2[2]; bf16x8 v; } b0, b1;
            b0.d2[0] = *(const unsigned long long*)(rowp + (((q * 4 + 0) ^ xr) << 4) + (h << 3));
            b0.d2[1] = *(const unsigned long long*)(rowp + (((q * 4 + 1) ^ xr) << 4) + (h << 3));
            b1.d2[0] = *(const unsigned long long*)(rowp + (((q * 4 + 2) ^ xr) << 4) + (h << 3));
            b1.d2[1] = *(const unsigned long long*)(rowp + (((q * 4 + 3) ^ xr) << 4) + (h << 3));
            num[c] = __builtin_amdgcn_mfma_f32_32x32x16_bf16(pa0.v, b0.v, num[c], 0, 0, 0);
            num[c] = __builtin_amdgcn_mfma_f32_32x32x16_bf16(pa1.v, b1.v, num[c], 0, 0, 0);
        }
        mw = mw_n;
        __syncthreads();
    }

    // ---- epilogue: combine 4 quarter-partials
    rs += __shfl_xor(rs, 32);
    float* RSB = (float*)(LDSC + 131072);
    if (l < 32) RSB[(s * 32 + l31) * 4 + q] = rs;
    float* PART = (float*)LDSC;   // aliases dead tile buffers
#pragma unroll
    for (int c = 0; c < 4; ++c)
#pragma unroll
        for (int r = 0; r < 16; ++r) {
            int m = (r & 3) + 8 * (r >> 2) + 4 * h;
            PART[q * 8192 + (s * 32 + m) * 128 + c * 32 + l31] = num[c][r];
        }
    __syncthreads();
    {
        int row = t >> 3, colbase = (t & 7) * 16;
        float accv[16];
#pragma unroll
        for (int k = 0; k < 16; ++k) accv[k] = 0.f;
#pragma unroll
        for (int q4 = 0; q4 < 4; ++q4)
#pragma unroll
            for (int k = 0; k < 4; ++k) {
                f32x4 pv = *(const f32x4*)(PART + q4 * 8192 + row * 128 + colbase + k * 4);
                accv[k * 4 + 0] += pv[0]; accv[k * 4 + 1] += pv[1];
                accv[k * 4 + 2] += pv[2]; accv[k * 4 + 3] += pv[3];
            }
        float den = RSB[row * 4 + 0] + RSB[row * 4 + 1] + RSB[row * 4 + 2] + RSB[row * 4 + 3] + 1e-6f;
        float sc = 1.0f / den;
        bf16x8 o0, o1;
#pragma unroll
        for (int k = 0; k < 8; ++k) { o0[k] = (bf16)(accv[k] * sc); o1[k] = (bf16)(accv[8 + k] * sc); }
        bf16* dst = aggG + ((size_t)(b * N_ + rowbase + row)) * 128 + colbase;
        *(bf16x8*)dst = o0;
        *(bf16x8*)(dst + 8) = o1;
    }
}

// ---------------- K4: out = normalize(agg@Wl + bl + xg@Wr) ----------------
__global__ __launch_bounds__(256) void k_out(const bf16* __restrict__ aggG,
        const bf16* __restrict__ xgG, const bf16* __restrict__ wlT,
        const bf16* __restrict__ wrT, const float* __restrict__ blv,
        float* __restrict__ out) {
    __shared__ bf16 wl[128][136];
    __shared__ bf16 wr[128][136];
    __shared__ bf16 ag[64][136];
    __shared__ bf16 xgl[64][136];
    const int t = threadIdx.x, lane = t & 63, w = t >> 6;
    const int rowbase = blockIdx.x * 64;
    {
        int r = t >> 1, h = t & 1;
#pragma unroll
        for (int k = 0; k < 64; k += 8) {
            *(bf16x8*)&wl[r][h * 64 + k] = *(const bf16x8*)(wlT + r * 128 + h * 64 + k);
            *(bf16x8*)&wr[r][h * 64 + k] = *(const bf16x8*)(wrT + r * 128 + h * 64 + k);
        }
        int rl = t >> 2, q = t & 3;
        const bf16* s1 = aggG + ((size_t)(rowbase + rl)) * 128 + q * 32;
        const bf16* s2 = xgG + ((size_t)(rowbase + rl)) * 128 + q * 32;
#pragma unroll
        for (int k = 0; k < 32; k += 8) {
            *(bf16x8*)&ag[rl][q * 32 + k] = *(const bf16x8*)(s1 + k);
            *(bf16x8*)&xgl[rl][q * 32 + k] = *(const bf16x8*)(s2 + k);
        }
    }
    __syncthreads();
    const int cIdx = lane & 15, g4 = lane >> 4;
    bf16x8 aa[4], ax[4];
#pragma unroll
    for (int c = 0; c < 4; ++c) {
        aa[c] = *(const bf16x8*)&ag[w * 16 + cIdx][c * 32 + g4 * 8];
        ax[c] = *(const bf16x8*)&xgl[w * 16 + cIdx][c * 32 + g4 * 8];
    }
    f32x4 acc[8];
    float ss[4] = {0.f, 0.f, 0.f, 0.f};
#pragma unroll
    for (int osub = 0; osub < 8; ++osub) {
        float bb = blv[osub * 16 + cIdx];
        f32x4 a = {bb, bb, bb, bb};
#pragma unroll
        for (int c = 0; c < 4; ++c) {
            bf16x8 b1 = *(const bf16x8*)&wl[osub * 16 + cIdx][c * 32 + g4 * 8];
            a = __builtin_amdgcn_mfma_f32_16x16x32_bf16(aa[c], b1, a, 0, 0, 0);
            bf16x8 b2 = *(const bf16x8*)&wr[osub * 16 + cIdx][c * 32 + g4 * 8];
            a = __builtin_amdgcn_mfma_f32_16x16x32_bf16(ax[c], b2, a, 0, 0, 0);
        }
        acc[osub] = a;
#pragma unroll
        for (int r = 0; r < 4; ++r) ss[r] += a[r] * a[r];
    }
#pragma unroll
    for (int r = 0; r < 4; ++r) {
        ss[r] += __shfl_xor(ss[r], 1);
        ss[r] += __shfl_xor(ss[r], 2);
        ss[r] += __shfl_xor(ss[r], 4);
        ss[r] += __shfl_xor(ss[r], 8);
    }
    float sc[4];
#pragma unroll
    for (int r = 0; r < 4; ++r) sc[r] = 1.0f / fmaxf(sqrtf(ss[r]), 1e-12f);
#pragma unroll
    for (int osub = 0; osub < 8; ++osub)
#pragma unroll
        for (int r = 0; r < 4; ++r) {
            size_t row = (size_t)rowbase + w * 16 + g4 * 4 + r;
            out[row * 128 + osub * 16 + cIdx] = acc[osub][r] * sc[r];
        }
}

extern "C" void kernel_launch(void* const* d_in, const int* in_sizes, int n_in,
                              void* d_out, int out_size, void* d_ws, size_t ws_size,
                              hipStream_t stream) {
    const float* x   = (const float*)d_in[0];
    const float* A   = (const float*)d_in[1];
    const float* Wqk = (const float*)d_in[2];
    const float* bqk = (const float*)d_in[3];
    const float* Wl  = (const float*)d_in[4];
    const float* bl  = (const float*)d_in[5];
    const float* Wr  = (const float*)d_in[6];
    const float* Wd  = (const float*)d_in[7];
    const float* bd  = (const float*)d_in[8];
    float* out = (float*)d_out;
    char* ws = (char*)d_ws;

    unsigned int* maskG = (unsigned int*)ws;                      // 4 MB
    float* degG = (float*)(ws + (4 << 20));                       // 64 KB
    bf16* wqkT  = (bf16*)(ws + (5 << 20));                        // 32 KB
    bf16* wlT   = (bf16*)(ws + (5 << 20) + 32768);
    bf16* wrT   = (bf16*)(ws + (5 << 20) + 65536);
    bf16* qkG   = (bf16*)(ws + (6 << 20));                        // 4 MB
    bf16* xgG   = (bf16*)(ws + (10 << 20));                       // 4 MB
    bf16* xgTG  = (bf16*)(ws + (14 << 20));                       // 4 MB
    bf16* aggG  = (bf16*)(ws + (18 << 20));                       // 4 MB

    hipLaunchKernelGGL(k_wtrans, dim3(24), dim3(256), 0, stream, Wqk, Wl, Wr, wqkT, wlT, wrT);
    hipLaunchKernelGGL(k_deg_mask, dim3(NROW), dim3(256), 0, stream, A, maskG, degG);
    hipLaunchKernelGGL(k_proj, dim3(NROW / 64), dim3(256), 0, stream,
                       x, degG, Wd, bd, wqkT, bqk, qkG, xgG, xgTG);
    hipLaunchKernelGGL(k_attn, dim3(NROW / 64), dim3(512), 0, stream, qkG, xgTG, maskG, aggG);
    hipLaunchKernelGGL(k_out, dim3(NROW / 64), dim3(256), 0, stream, aggG, xgG, wlT, wrT, bl, out);
}

// Round 5
// 253.941 us; speedup vs baseline: 1.2012x; 1.0050x over previous
//
#include <hip/hip_runtime.h>
#include <hip/hip_bf16.h>

#define B_ 8
#define N_ 2048
#define D_ 128
#define NROW (B_*N_)   // 16384

typedef __bf16 bf16;
typedef __bf16 bf16x8 __attribute__((ext_vector_type(8)));
typedef float f32x4 __attribute__((ext_vector_type(4)));
typedef float f32x16 __attribute__((ext_vector_type(16)));

__device__ __forceinline__ float sigmoidf_(float x) {
    return 1.0f / (1.0f + __expf(-x));
}

__device__ __forceinline__ void g2l16(const bf16* g, void* l) {
    __builtin_amdgcn_global_load_lds(
        (const __attribute__((address_space(1))) unsigned int*)g,
        (__attribute__((address_space(3))) unsigned int*)l, 16, 0, 0);
}

__device__ __forceinline__ unsigned pk_bf16(float a, float b) {
    union { bf16 h[2]; unsigned u; } t;
    t.h[0] = (bf16)a; t.h[1] = (bf16)b;
    return t.u;
}

// ---------------- K0: transpose W_qk, W_l, W_r -> bf16 [out][in] ----------------
__global__ __launch_bounds__(256) void k_wtrans(const float* __restrict__ Wqk,
        const float* __restrict__ Wl, const float* __restrict__ Wr,
        bf16* __restrict__ wqkT, bf16* __restrict__ wlT, bf16* __restrict__ wrT) {
    int m = blockIdx.x >> 3;       // 0..2
    int chunk = blockIdx.x & 7;    // 0..7
    const float* W = (m == 0) ? Wqk : (m == 1 ? Wl : Wr);
    bf16* WT = (m == 0) ? wqkT : (m == 1 ? wlT : wrT);
#pragma unroll
    for (int e = 0; e < 8; ++e) {
        int idx = e * 256 + threadIdx.x;   // 0..2047
        int ol = idx >> 7;                 // 0..15
        int i  = idx & 127;
        int o = chunk * 16 + ol;
        WT[o * 128 + i] = (bf16)W[i * 128 + o];
    }
}

// ---------------- K1: deg + bitmask; one wave per row, 4 rows/block ----------------
__global__ __launch_bounds__(256) void k_deg_mask(const float* __restrict__ A,
        unsigned int* __restrict__ mask, float* __restrict__ deg) {
    const int w = threadIdx.x >> 6, lane = threadIdx.x & 63;
    const int row = blockIdx.x * 4 + w;
    const float* a = A + (size_t)row * N_;
    unsigned int* mrow = mask + (size_t)row * (N_ / 32);
    int cnt = 0;
#pragma unroll
    for (int i = 0; i < N_ / 256; ++i) {     // 8 iters, 256 cols each
        float4 v = *(const float4*)(a + i * 256 + lane * 4);
        unsigned long long nib = (unsigned long long)((v.x != 0.f) | ((v.y != 0.f) << 1) |
                                                      ((v.z != 0.f) << 2) | ((v.w != 0.f) << 3));
        unsigned long long p = nib << ((lane & 15) * 4);
        p |= __shfl_xor(p, 1);
        p |= __shfl_xor(p, 2);
        p |= __shfl_xor(p, 4);
        p |= __shfl_xor(p, 8);
        if ((lane & 15) == 0) {
            int idx = i * 8 + (lane >> 4) * 2;
            mrow[idx] = (unsigned int)p;
            mrow[idx + 1] = (unsigned int)(p >> 32);
            cnt += __popcll(p);
        }
    }
    cnt += __shfl_xor(cnt, 16);
    cnt += __shfl_xor(cnt, 32);
    if (lane == 0) deg[row] = (float)cnt;
}

// ---------------- K2: gate, xg, QK = sigmoid(xg@Wqk+bqk); write qk, xg, xgT (bf16) ----------------
__global__ __launch_bounds__(256) void k_proj(const float* __restrict__ x,
        const float* __restrict__ deg, const float* __restrict__ Wd,
        const float* __restrict__ bd, const bf16* __restrict__ wqkT,
        const float* __restrict__ bqk,
        bf16* __restrict__ qkG, bf16* __restrict__ xgG, bf16* __restrict__ xgTG) {
    __shared__ bf16 wq[128][136];
    __shared__ bf16 xgl[64][136];
    const int t = threadIdx.x, lane = t & 63, w = t >> 6;
    const int rowbase = blockIdx.x * 64;
    {
        int r = t >> 1, h = t & 1;
        const bf16* src = wqkT + r * 128 + h * 64;
#pragma unroll
        for (int k = 0; k < 64; k += 8)
            *(bf16x8*)&wq[r][h * 64 + k] = *(const bf16x8*)(src + k);
    }
#pragma unroll
    for (int e = 0; e < 32; ++e) {
        int idx = e * 256 + t;        // 0..8191
        int rl = idx >> 7;            // 0..63
        int d  = idx & 127;
        size_t fr = (size_t)rowbase + rl;
        float g = sigmoidf_(deg[fr] * Wd[d] + bd[d]);
        float v = x[fr * 128 + d] * g;
        bf16 bv = (bf16)v;
        xgl[rl][d] = bv;
        xgG[fr * 128 + d] = bv;
    }
    __syncthreads();
    const int cIdx = lane & 15, g4 = lane >> 4;
    bf16x8 ax[4];
#pragma unroll
    for (int c = 0; c < 4; ++c)
        ax[c] = *(const bf16x8*)&xgl[w * 16 + cIdx][c * 32 + g4 * 8];
#pragma unroll
    for (int dsub = 0; dsub < 8; ++dsub) {
        f32x4 acc = {0.f, 0.f, 0.f, 0.f};
#pragma unroll
        for (int c = 0; c < 4; ++c) {
            bf16x8 bw = *(const bf16x8*)&wq[dsub * 16 + cIdx][c * 32 + g4 * 8];
            acc = __builtin_amdgcn_mfma_f32_16x16x32_bf16(ax[c], bw, acc, 0, 0, 0);
        }
        int col = dsub * 16 + cIdx;
        float bb = bqk[col];
#pragma unroll
        for (int r = 0; r < 4; ++r) {
            size_t row = (size_t)rowbase + w * 16 + g4 * 4 + r;
            qkG[row * 128 + col] = (bf16)sigmoidf_(acc[r] + bb);
        }
    }
    {
        int b = rowbase / N_;
        int nbase = rowbase % N_;
#pragma unroll
        for (int e = 0; e < 32; ++e) {
            int idx = e * 256 + t;   // 0..8191
            int d  = idx >> 6;       // 0..127
            int nl = idx & 63;
            xgTG[((size_t)b * 128 + d) * N_ + nbase + nl] = xgl[nl][d];
        }
    }
}

// ---------------- K3+K4 fused: masked attention + output proj + L2 normalize ----------------
// Main loop identical to R4's k_attn (verified). Epilogue keeps agg in LDS (bf16,
// padded [64][136]); then stages wlT/wrT/xg into the dead tile region and finishes
// out = normalize(agg@Wl + bl + xg@Wr) in-kernel. No aggG roundtrip, one less launch.
// LDS map (bytes):
//   main loop: [0,65536) QKJ dbuf; [65536,131072) XGT dbuf; [131072,132096) RSB
//   epilogue:  PART[4][64][128] f32 aliases [0,131072)
//   K4 phase:  wl [128][136] @0 (34816); wr @34816; xgl [64][136] @69632 (17408);
//              SSB[2][64] f32 @87040; AGL [64][136] bf16 @132096 (17408) -> total 149504
__global__ __launch_bounds__(512, 2) void k_attn_out(const bf16* __restrict__ qkG,
        const bf16* __restrict__ xgTG, const unsigned int* __restrict__ mask32,
        const bf16* __restrict__ xgG, const bf16* __restrict__ wlT,
        const bf16* __restrict__ wrT, const float* __restrict__ blv,
        float* __restrict__ out) {
    __shared__ __align__(16) char LDSC[149504];
    const int t = threadIdx.x, l = t & 63, w = t >> 6;
    const int h = l >> 5, l31 = l & 31;
    const int q = w >> 1, s = w & 1;
    const int bid = (blockIdx.x & 7) * 32 + (blockIdx.x >> 3);   // XCD swizzle (bijective)
    const int b = bid >> 5;
    const int rowbase = (bid & 31) * 64;
    const int R0 = rowbase + s * 32;
    const float inv = 0.08838834764831845f;  // 1/sqrt(128)

    auto do_stage = [&](int jb, int bbuf) {
        char* qdst = LDSC + bbuf * 32768 + w * 4096;
        char* xdst = LDSC + 65536 + bbuf * 32768 + w * 4096;
#pragma unroll
        for (int i = 0; i < 4; ++i) {
            int G = w * 256 + i * 64 + l;
            int j = G >> 4, g = G & 15;
            const bf16* src = qkG + ((size_t)(b * N_ + jb + j)) * 128 + ((g ^ (j & 7)) << 3);
            g2l16(src, qdst + i * 1024);
            const bf16* src2 = xgTG + ((size_t)b * 128 + j) * N_ + jb + ((g ^ (j & 7)) << 3);
            g2l16(src2, xdst + i * 1024);
        }
    };

    // QK_i B-fragments: lane holds col i = R0+l31, k = d
    bf16x8 qki[8];
    {
        const bf16* srcB = qkG + ((size_t)(b * N_ + R0 + l31)) * 128 + h * 8;
#pragma unroll
        for (int sl = 0; sl < 8; ++sl) qki[sl] = *(const bf16x8*)(srcB + sl * 16);
    }
    const unsigned int* mrow = mask32 + ((size_t)(b * N_ + R0 + l31)) * (N_ / 32) + q;
    unsigned int mw = mrow[0];

    do_stage(0, 0);
    __syncthreads();

    f32x16 num[4]; num[0] = f32x16{}; num[1] = f32x16{}; num[2] = f32x16{}; num[3] = f32x16{};
    float rs = 0.f;

    for (int ts = 0; ts < 16; ++ts) {
        const int bb = ts & 1;
        unsigned int mw_n = 0;
        if (ts < 15) {
            mw_n = mrow[(ts + 1) * 4];
            do_stage((ts + 1) * 128, bb ^ 1);
        }
        const char* qb = LDSC + bb * 32768;
        const char* xb = LDSC + 65536 + bb * 32768;
        // ---- S^T = QK_j @ QK_i^T
        f32x16 st{};
        const int rowb = (q * 32 + l31) * 256;
#pragma unroll
        for (int sl = 0; sl < 8; ++sl) {
            bf16x8 aj = *(const bf16x8*)(qb + rowb + ((((sl << 1) | h) ^ (l & 7)) << 4));
            st = __builtin_amdgcn_mfma_f32_32x32x16_bf16(aj, qki[sl], st, 0, 0, 0);
        }
        // ---- mask + scale + rowsum + pack (C-layout order)
        unsigned int mws = mw >> (h * 4);
        unsigned int wpk[8];
#pragma unroll
        for (int r2 = 0; r2 < 8; ++r2) {
            const int r = r2 * 2;
            const int bit0 = (r & 3) + 8 * (r >> 2);
            float p0 = ((mws >> bit0) & 1u) ? st[r] * inv : 0.f;
            float p1 = ((mws >> (bit0 + 1)) & 1u) ? st[r + 1] * inv : 0.f;
            rs += p0 + p1;
            wpk[r2] = pk_bf16(p0, p1);
        }
        union { unsigned int u[4]; bf16x8 v; } pa0, pa1;
        pa0.u[0] = wpk[0]; pa0.u[1] = wpk[1]; pa0.u[2] = wpk[2]; pa0.u[3] = wpk[3];
        pa1.u[0] = wpk[4]; pa1.u[1] = wpk[5]; pa1.u[2] = wpk[6]; pa1.u[3] = wpk[7];
        // ---- num += P @ xg_j : B loaded j-matched to J(h,e)=4h+(e&3)+8*(e>>2)
        const int xr = l & 7;
#pragma unroll
        for (int c = 0; c < 4; ++c) {
            const char* rowp = xb + (c * 32 + l31) * 256;
            union { unsigned long long d2[2]; bf16x8 v; } b0, b1;
            b0.d2[0] = *(const unsigned long long*)(rowp + (((q * 4 + 0) ^ xr) << 4) + (h << 3));
            b0.d2[1] = *(const unsigned long long*)(rowp + (((q * 4 + 1) ^ xr) << 4) + (h << 3));
            b1.d2[0] = *(const unsigned long long*)(rowp + (((q * 4 + 2) ^ xr) << 4) + (h << 3));
            b1.d2[1] = *(const unsigned long long*)(rowp + (((q * 4 + 3) ^ xr) << 4) + (h << 3));
            num[c] = __builtin_amdgcn_mfma_f32_32x32x16_bf16(pa0.v, b0.v, num[c], 0, 0, 0);
            num[c] = __builtin_amdgcn_mfma_f32_32x32x16_bf16(pa1.v, b1.v, num[c], 0, 0, 0);
        }
        mw = mw_n;
        __syncthreads();
    }

    // ---- epilogue: combine 4 quarter-partials; agg stays in LDS (bf16)
    rs += __shfl_xor(rs, 32);
    float* RSB = (float*)(LDSC + 131072);
    if (l < 32) RSB[(s * 32 + l31) * 4 + q] = rs;
    float* PART = (float*)LDSC;   // aliases dead tile buffers
#pragma unroll
    for (int c = 0; c < 4; ++c)
#pragma unroll
        for (int r = 0; r < 16; ++r) {
            int m = (r & 3) + 8 * (r >> 2) + 4 * h;
            PART[q * 8192 + (s * 32 + m) * 128 + c * 32 + l31] = num[c][r];
        }
    __syncthreads();
    {
        int row = t >> 3, colbase = (t & 7) * 16;
        float accv[16];
#pragma unroll
        for (int k = 0; k < 16; ++k) accv[k] = 0.f;
#pragma unroll
        for (int q4 = 0; q4 < 4; ++q4)
#pragma unroll
            for (int k = 0; k < 4; ++k) {
                f32x4 pv = *(const f32x4*)(PART + q4 * 8192 + row * 128 + colbase + k * 4);
                accv[k * 4 + 0] += pv[0]; accv[k * 4 + 1] += pv[1];
                accv[k * 4 + 2] += pv[2]; accv[k * 4 + 3] += pv[3];
            }
        float den = RSB[row * 4 + 0] + RSB[row * 4 + 1] + RSB[row * 4 + 2] + RSB[row * 4 + 3] + 1e-6f;
        float sc = 1.0f / den;
        bf16x8 o0, o1;
#pragma unroll
        for (int k = 0; k < 8; ++k) { o0[k] = (bf16)(accv[k] * sc); o1[k] = (bf16)(accv[8 + k] * sc); }
        char* AGL = LDSC + 132096;          // [64][136] bf16
        *(bf16x8*)(AGL + row * 272 + colbase * 2) = o0;
        *(bf16x8*)(AGL + row * 272 + colbase * 2 + 16) = o1;
    }
    __syncthreads();
    // ---- stage wl, wr (padded [128][136]) and xg tile into dead PART region
    {
        bf16* wlds = (bf16*)LDSC;
        bf16* wrds = (bf16*)(LDSC + 34816);
        bf16* xgl  = (bf16*)(LDSC + 69632);
        int r = t >> 2, hq = t & 3;
        const bf16* s1 = wlT + r * 128 + hq * 32;
        const bf16* s2 = wrT + r * 128 + hq * 32;
#pragma unroll
        for (int k = 0; k < 32; k += 8) {
            *(bf16x8*)&wlds[r * 136 + hq * 32 + k] = *(const bf16x8*)(s1 + k);
            *(bf16x8*)&wrds[r * 136 + hq * 32 + k] = *(const bf16x8*)(s2 + k);
        }
        int rl = t >> 3, cb = (t & 7) * 16;
        const bf16* s3 = xgG + ((size_t)(b * N_ + rowbase + rl)) * 128 + cb;
        *(bf16x8*)&xgl[rl * 136 + cb] = *(const bf16x8*)s3;
        *(bf16x8*)&xgl[rl * 136 + cb + 8] = *(const bf16x8*)(s3 + 8);
    }
    __syncthreads();
    // ---- K4 phase: 8 waves = 4 row-tiles x 2 osub-halves
    {
        const bf16* wlds = (const bf16*)LDSC;
        const bf16* wrds = (const bf16*)(LDSC + 34816);
        const bf16* xgl  = (const bf16*)(LDSC + 69632);
        const bf16* AGLb = (const bf16*)(LDSC + 132096);
        float* SSB = (float*)(LDSC + 87040);
        const int cIdx = l & 15, g4 = l >> 4;
        const int rt = (w & 3) * 16;      // block-local row-tile base
        const int oh = w >> 2;            // osub half (0..1)
        bf16x8 aa[4], ax[4];
#pragma unroll
        for (int c = 0; c < 4; ++c) {
            aa[c] = *(const bf16x8*)(AGLb + (rt + cIdx) * 136 + c * 32 + g4 * 8);
            ax[c] = *(const bf16x8*)(xgl + (rt + cIdx) * 136 + c * 32 + g4 * 8);
        }
        f32x4 acc[4];
        float ss[4] = {0.f, 0.f, 0.f, 0.f};
#pragma unroll
        for (int os = 0; os < 4; ++os) {
            int col = (oh * 4 + os) * 16 + cIdx;
            float bb = blv[col];
            f32x4 a = {bb, bb, bb, bb};
#pragma unroll
            for (int c = 0; c < 4; ++c) {
                bf16x8 b1 = *(const bf16x8*)(wlds + col * 136 + c * 32 + g4 * 8);
                a = __builtin_amdgcn_mfma_f32_16x16x32_bf16(aa[c], b1, a, 0, 0, 0);
                bf16x8 b2 = *(const bf16x8*)(wrds + col * 136 + c * 32 + g4 * 8);
                a = __builtin_amdgcn_mfma_f32_16x16x32_bf16(ax[c], b2, a, 0, 0, 0);
            }
            acc[os] = a;
#pragma unroll
            for (int r = 0; r < 4; ++r) ss[r] += a[r] * a[r];
        }
#pragma unroll
        for (int r = 0; r < 4; ++r) {
            ss[r] += __shfl_xor(ss[r], 1);
            ss[r] += __shfl_xor(ss[r], 2);
            ss[r] += __shfl_xor(ss[r], 4);
            ss[r] += __shfl_xor(ss[r], 8);
        }
        if (cIdx == 0)
#pragma unroll
            for (int r = 0; r < 4; ++r) SSB[oh * 64 + rt + g4 * 4 + r] = ss[r];
        __syncthreads();
#pragma unroll
        for (int r = 0; r < 4; ++r) {
            int row_l = rt + g4 * 4 + r;
            float tot = SSB[row_l] + SSB[64 + row_l];
            float sc = 1.0f / fmaxf(sqrtf(tot), 1e-12f);
#pragma unroll
            for (int os = 0; os < 4; ++os) {
                size_t grow = (size_t)(b * N_ + rowbase + row_l);
                out[grow * 128 + (oh * 4 + os) * 16 + cIdx] = acc[os][r] * sc;
            }
        }
    }
}

extern "C" void kernel_launch(void* const* d_in, const int* in_sizes, int n_in,
                              void* d_out, int out_size, void* d_ws, size_t ws_size,
                              hipStream_t stream) {
    const float* x   = (const float*)d_in[0];
    const float* A   = (const float*)d_in[1];
    const float* Wqk = (const float*)d_in[2];
    const float* bqk = (const float*)d_in[3];
    const float* Wl  = (const float*)d_in[4];
    const float* bl  = (const float*)d_in[5];
    const float* Wr  = (const float*)d_in[6];
    const float* Wd  = (const float*)d_in[7];
    const float* bd  = (const float*)d_in[8];
    float* out = (float*)d_out;
    char* ws = (char*)d_ws;

    unsigned int* maskG = (unsigned int*)ws;                      // 4 MB
    float* degG = (float*)(ws + (4 << 20));                       // 64 KB
    bf16* wqkT  = (bf16*)(ws + (5 << 20));                        // 32 KB
    bf16* wlT   = (bf16*)(ws + (5 << 20) + 32768);
    bf16* wrT   = (bf16*)(ws + (5 << 20) + 65536);
    bf16* qkG   = (bf16*)(ws + (6 << 20));                        // 4 MB
    bf16* xgG   = (bf16*)(ws + (10 << 20));                       // 4 MB
    bf16* xgTG  = (bf16*)(ws + (14 << 20));                       // 4 MB

    hipLaunchKernelGGL(k_wtrans, dim3(24), dim3(256), 0, stream, Wqk, Wl, Wr, wqkT, wlT, wrT);
    hipLaunchKernelGGL(k_deg_mask, dim3(NROW / 4), dim3(256), 0, stream, A, maskG, degG);
    hipLaunchKernelGGL(k_proj, dim3(NROW / 64), dim3(256), 0, stream,
                       x, degG, Wd, bd, wqkT, bqk, qkG, xgG, xgTG);
    hipLaunchKernelGGL(k_attn_out, dim3(NROW / 64), dim3(512), 0, stream,
                       qkG, xgTG, maskG, xgG, wlT, wrT, bl, out);
}